// Round 5
// baseline (106.115 us; speedup 1.0000x reference)
//
#include <hip/hip_runtime.h>

#define BINS 256
#define EMBV 64          // EMB/4 float4s per row
#define BH   8           // 2*4 flattened batch

typedef float f32x4 __attribute__((ext_vector_type(4)));

// out[bh][i][j][d] = (s_i+s_j)*0.5 + s_i*s_j + T[|i-j|][d]
//
// One block per (bh,i). XCD-grouped mapping (R4, -11%): bh = blk&7 pins each
// bh's working set (512KB) to one XCD's L2. R5 single-variable change:
// non-temporal stores -> write stream doesn't allocate in L2, so it neither
// evicts the input set nor competes for L2 bandwidth.
__global__ __launch_bounds__(256) void outputhead_kernel(
        const f32x4* __restrict__ seq4,   // [BH][BINS][EMBV]
        const f32x4* __restrict__ tab4,   // [256][EMBV]
        f32x4* __restrict__ out4)         // [BH][BINS][BINS][EMBV]
{
    const int blk = blockIdx.x;
    const int bh  = blk & 7;           // XCD-grouped: one bh per XCD
    const int i   = blk >> 3;          // consecutive same-XCD blocks -> adjacent i
    const int t   = threadIdx.x;
    const int d4  = t & 63;
    const int tj  = t >> 6;            // 0..3

    const f32x4 si = seq4[(bh * BINS + i) * EMBV + d4];

    const size_t seq_bh_base  = (size_t)bh * BINS * EMBV;
    const size_t out_row_base = ((size_t)(bh * BINS + i)) * BINS * EMBV;

    #pragma unroll 4
    for (int jb = 0; jb < BINS; jb += 4) {
        const int j    = jb + tj;
        const int dist = (i > j) ? (i - j) : (j - i);

        const f32x4 sj = seq4[seq_bh_base + (size_t)j * EMBV + d4];
        const f32x4 tv = tab4[(size_t)dist * EMBV + d4];

        const f32x4 o = (si + sj) * 0.5f + si * sj + tv;

        __builtin_nontemporal_store(o, &out4[out_row_base + (size_t)j * EMBV + d4]);
    }
}

extern "C" void kernel_launch(void* const* d_in, const int* in_sizes, int n_in,
                              void* d_out, int out_size, void* d_ws, size_t ws_size,
                              hipStream_t stream) {
    const f32x4* seq4 = (const f32x4*)d_in[0];  // (2,4,256,256) fp32
    const f32x4* tab4 = (const f32x4*)d_in[1];  // (256,256) fp32
    f32x4* out4 = (f32x4*)d_out;                // (2,4,256,256,256) fp32

    dim3 grid(BH * BINS);   // 2048 blocks
    dim3 block(256);
    outputhead_kernel<<<grid, block, 0, stream>>>(seq4, tab4, out4);
}

// Round 6
// 102.244 us; speedup vs baseline: 1.0379x; 1.0379x over previous
//
#include <hip/hip_runtime.h>

#define BINS 256
#define EMBV 64          // EMB/4 float4s per row
#define BH   8           // 2*4 flattened batch

typedef float f32x4 __attribute__((ext_vector_type(4)));

// out[bh][i][j][d] = (s_i+s_j)*0.5 + s_i*s_j + T[|i-j|][d]
//
// R4 structure (98.2us) + 2-row blocking: each block computes output rows
// i0 = 2p and i0+1, sharing every s_j load between the two rows
// (loads/output 32B -> 24B) and issuing 2 independent contiguous stores
// per iteration. XCD-grouped mapping kept: bh = blk&7 pins each bh's
// 512KB read set to one XCD's L2. nt stores reverted (R5: -8%).
// 512 threads: d4 = t&63 float4 lane, tj = t>>6 j-subslot (0..7).
__global__ __launch_bounds__(512) void outputhead_kernel(
        const f32x4* __restrict__ seq4,   // [BH][BINS][EMBV]
        const f32x4* __restrict__ tab4,   // [256][EMBV]
        f32x4* __restrict__ out4)         // [BH][BINS][BINS][EMBV]
{
    const int blk = blockIdx.x;
    const int bh  = blk & 7;            // XCD-grouped: one bh per XCD
    const int p   = blk >> 3;           // 0..127 row-pair
    const int i0  = p * 2;
    const int i1  = i0 + 1;
    const int t   = threadIdx.x;
    const int d4  = t & 63;
    const int tj  = t >> 6;             // 0..7

    const size_t seq_bh_base = (size_t)bh * BINS * EMBV;

    const f32x4 si0 = seq4[seq_bh_base + (size_t)i0 * EMBV + d4];
    const f32x4 si1 = seq4[seq_bh_base + (size_t)i1 * EMBV + d4];

    const size_t out_row0 = ((size_t)(bh * BINS + i0)) * BINS * EMBV;
    const size_t out_row1 = out_row0 + (size_t)BINS * EMBV;

    #pragma unroll 4
    for (int jb = 0; jb < BINS; jb += 8) {
        const int j     = jb + tj;
        const int dist0 = (i0 > j) ? (i0 - j) : (j - i0);
        const int dist1 = (i1 > j) ? (i1 - j) : (j - i1);

        const f32x4 sj  = seq4[seq_bh_base + (size_t)j * EMBV + d4];
        const f32x4 tv0 = tab4[(size_t)dist0 * EMBV + d4];
        const f32x4 tv1 = tab4[(size_t)dist1 * EMBV + d4];

        const f32x4 o0 = (si0 + sj) * 0.5f + si0 * sj + tv0;
        const f32x4 o1 = (si1 + sj) * 0.5f + si1 * sj + tv1;

        out4[out_row0 + (size_t)j * EMBV + d4] = o0;
        out4[out_row1 + (size_t)j * EMBV + d4] = o1;
    }
}

extern "C" void kernel_launch(void* const* d_in, const int* in_sizes, int n_in,
                              void* d_out, int out_size, void* d_ws, size_t ws_size,
                              hipStream_t stream) {
    const f32x4* seq4 = (const f32x4*)d_in[0];  // (2,4,256,256) fp32
    const f32x4* tab4 = (const f32x4*)d_in[1];  // (256,256) fp32
    f32x4* out4 = (f32x4*)d_out;                // (2,4,256,256,256) fp32

    dim3 grid(BH * 128);   // 1024 blocks: 8 bh x 128 row-pairs
    dim3 block(512);
    outputhead_kernel<<<grid, block, 0, stream>>>(seq4, tab4, out4);
}